// Round 1
// baseline (211.650 us; speedup 1.0000x reference)
//
#include <hip/hip_runtime.h>
#include <stdint.h>

// ----------------------------------------------------------------------------
// SparseKVCache: keep top-k elements by |x| (k = n/2), zero the rest.
// Exact radix-select on bits(|x|) (monotone for non-negative floats), with
// jax.lax.top_k stable tie handling (ties at threshold keep smallest indices).
// ----------------------------------------------------------------------------

#define NBLK 2048
#define NTHR 256

// ws layout (uint32 words)
#define H1_OFF   0        // 2048 bins: bits 30..20
#define H2_OFF   2048     // 2048 bins: bits 19..9
#define H3_OFF   4096     // 512  bins: bits 8..0
#define SEL_OFF  4608     // [0]=b1 [1]=rem1 [2]=b2 [3]=rem2 [4]=t [5]=j [6]=gatherCnt
#define GIDX_OFF 4624     // gathered indices (22-bit-prefix matches)
#define GATHER_CAP 8192
#define GLOW_OFF (GIDX_OFF + GATHER_CAP)   // gathered low-9-bits
#define KEEP_OFF (GLOW_OFF + GATHER_CAP)   // kept tie indices
#define KEEP_CAP 256
#define WS_WORDS (KEEP_OFF + KEEP_CAP)

__global__ void zero_ws_kernel(uint32_t* __restrict__ ws) {
    int i = blockIdx.x * blockDim.x + threadIdx.x;
    if (i < WS_WORDS) ws[i] = 0;
}

// ---------------- pass 1: histogram of bits 30..20 --------------------------
__global__ void hist1_kernel(const uint32_t* __restrict__ x, long long n,
                             uint32_t* __restrict__ ws) {
    __shared__ uint32_t lh[2048];
    for (int i = threadIdx.x; i < 2048; i += NTHR) lh[i] = 0;
    __syncthreads();
    long long n4 = n >> 2;
    const uint4* xv = (const uint4*)x;
    long long stride = (long long)gridDim.x * NTHR;
    for (long long i = (long long)blockIdx.x * NTHR + threadIdx.x; i < n4; i += stride) {
        uint4 v = xv[i];
        atomicAdd(&lh[(v.x & 0x7fffffffu) >> 20], 1u);
        atomicAdd(&lh[(v.y & 0x7fffffffu) >> 20], 1u);
        atomicAdd(&lh[(v.z & 0x7fffffffu) >> 20], 1u);
        atomicAdd(&lh[(v.w & 0x7fffffffu) >> 20], 1u);
    }
    if (blockIdx.x == 0 && threadIdx.x < (int)(n & 3)) {
        uint32_t u = x[(n4 << 2) + threadIdx.x] & 0x7fffffffu;
        atomicAdd(&lh[u >> 20], 1u);
    }
    __syncthreads();
    for (int i = threadIdx.x; i < 2048; i += NTHR)
        if (lh[i]) atomicAdd(&ws[H1_OFF + i], lh[i]);
}

// ---------------- generic select over a histogram (levels 1 & 2) ------------
// Finds bin b (scanning from high bins down) such that
// count(bins > b) < k <= count(bins >= b); writes b and rem = k - count(>b).
__global__ void select12_kernel(uint32_t* __restrict__ ws, int histOff, int nbins,
                                int kSel, uint32_t kConst, int outOff) {
    __shared__ uint32_t lh[2048];
    __shared__ uint32_t csum[NTHR];
    uint32_t k = (kSel >= 0) ? ws[SEL_OFF + kSel] : kConst;
    for (int i = threadIdx.x; i < nbins; i += NTHR) lh[i] = ws[histOff + i];
    __syncthreads();
    int cs = nbins / NTHR;
    uint32_t s = 0;
    for (int i = 0; i < cs; ++i) s += lh[threadIdx.x * cs + i];
    csum[threadIdx.x] = s;
    __syncthreads();
    if (threadIdx.x == 0) {
        uint32_t before = 0; int b = 0; uint32_t rem = 1;
        for (int c = NTHR - 1; c >= 0; --c) {
            if (before + csum[c] >= k) {
                for (int bb = c * cs + cs - 1; bb >= c * cs; --bb) {
                    uint32_t cnt = lh[bb];
                    if (before + cnt >= k) { b = bb; rem = k - before; break; }
                    before += cnt;
                }
                break;
            }
            before += csum[c];
        }
        ws[SEL_OFF + outOff]     = (uint32_t)b;
        ws[SEL_OFF + outOff + 1] = rem;
    }
}

// ---------------- pass 2: histogram of bits 19..9 within bin b1 -------------
__global__ void hist2_kernel(const uint32_t* __restrict__ x, long long n,
                             uint32_t* __restrict__ ws) {
    __shared__ uint32_t lh[2048];
    uint32_t b1 = ws[SEL_OFF + 0];
    for (int i = threadIdx.x; i < 2048; i += NTHR) lh[i] = 0;
    __syncthreads();
    long long n4 = n >> 2;
    const uint4* xv = (const uint4*)x;
    long long stride = (long long)gridDim.x * NTHR;
    for (long long i = (long long)blockIdx.x * NTHR + threadIdx.x; i < n4; i += stride) {
        uint4 v = xv[i];
        uint32_t u;
        u = v.x & 0x7fffffffu; if ((u >> 20) == b1) atomicAdd(&lh[(u >> 9) & 2047u], 1u);
        u = v.y & 0x7fffffffu; if ((u >> 20) == b1) atomicAdd(&lh[(u >> 9) & 2047u], 1u);
        u = v.z & 0x7fffffffu; if ((u >> 20) == b1) atomicAdd(&lh[(u >> 9) & 2047u], 1u);
        u = v.w & 0x7fffffffu; if ((u >> 20) == b1) atomicAdd(&lh[(u >> 9) & 2047u], 1u);
    }
    if (blockIdx.x == 0 && threadIdx.x < (int)(n & 3)) {
        uint32_t u = x[(n4 << 2) + threadIdx.x] & 0x7fffffffu;
        if ((u >> 20) == b1) atomicAdd(&lh[(u >> 9) & 2047u], 1u);
    }
    __syncthreads();
    for (int i = threadIdx.x; i < 2048; i += NTHR)
        if (lh[i]) atomicAdd(&ws[H2_OFF + i], lh[i]);
}

// -------- pass 3: histogram of bits 8..0 within 22-bit prefix + gather ------
__global__ void hist3_kernel(const uint32_t* __restrict__ x, long long n,
                             uint32_t* __restrict__ ws) {
    __shared__ uint32_t lh[512];
    uint32_t pfx = (ws[SEL_OFF + 0] << 11) | ws[SEL_OFF + 2];
    for (int i = threadIdx.x; i < 512; i += NTHR) lh[i] = 0;
    __syncthreads();
    long long n4 = n >> 2;
    const uint4* xv = (const uint4*)x;
    long long stride = (long long)gridDim.x * NTHR;
    for (long long i = (long long)blockIdx.x * NTHR + threadIdx.x; i < n4; i += stride) {
        uint4 v = xv[i];
        long long base = i << 2;
        uint32_t u;
        u = v.x & 0x7fffffffu;
        if ((u >> 9) == pfx) {
            atomicAdd(&lh[u & 511u], 1u);
            uint32_t p = atomicAdd(&ws[SEL_OFF + 6], 1u);
            if (p < GATHER_CAP) { ws[GIDX_OFF + p] = (uint32_t)(base + 0); ws[GLOW_OFF + p] = u & 511u; }
        }
        u = v.y & 0x7fffffffu;
        if ((u >> 9) == pfx) {
            atomicAdd(&lh[u & 511u], 1u);
            uint32_t p = atomicAdd(&ws[SEL_OFF + 6], 1u);
            if (p < GATHER_CAP) { ws[GIDX_OFF + p] = (uint32_t)(base + 1); ws[GLOW_OFF + p] = u & 511u; }
        }
        u = v.z & 0x7fffffffu;
        if ((u >> 9) == pfx) {
            atomicAdd(&lh[u & 511u], 1u);
            uint32_t p = atomicAdd(&ws[SEL_OFF + 6], 1u);
            if (p < GATHER_CAP) { ws[GIDX_OFF + p] = (uint32_t)(base + 2); ws[GLOW_OFF + p] = u & 511u; }
        }
        u = v.w & 0x7fffffffu;
        if ((u >> 9) == pfx) {
            atomicAdd(&lh[u & 511u], 1u);
            uint32_t p = atomicAdd(&ws[SEL_OFF + 6], 1u);
            if (p < GATHER_CAP) { ws[GIDX_OFF + p] = (uint32_t)(base + 3); ws[GLOW_OFF + p] = u & 511u; }
        }
    }
    if (blockIdx.x == 0 && threadIdx.x < (int)(n & 3)) {
        long long idx = (n4 << 2) + threadIdx.x;
        uint32_t u = x[idx] & 0x7fffffffu;
        if ((u >> 9) == pfx) {
            atomicAdd(&lh[u & 511u], 1u);
            uint32_t p = atomicAdd(&ws[SEL_OFF + 6], 1u);
            if (p < GATHER_CAP) { ws[GIDX_OFF + p] = (uint32_t)idx; ws[GLOW_OFF + p] = u & 511u; }
        }
    }
    __syncthreads();
    for (int i = threadIdx.x; i < 512; i += NTHR)
        if (lh[i]) atomicAdd(&ws[H3_OFF + i], lh[i]);
}

// -------- select level 3: final threshold t, tie list sorted by index -------
__global__ void select3_kernel(uint32_t* __restrict__ ws) {
    __shared__ uint32_t lh[512];
    __shared__ uint32_t csum[NTHR];
    __shared__ uint32_t tieIdx[KEEP_CAP];
    __shared__ uint32_t tieCnt;
    __shared__ uint32_t sb3, sj;
    uint32_t k = ws[SEL_OFF + 3];  // rem2
    for (int i = threadIdx.x; i < 512; i += NTHR) lh[i] = ws[H3_OFF + i];
    if (threadIdx.x == 0) tieCnt = 0;
    __syncthreads();
    const int cs = 512 / NTHR;  // 2
    uint32_t s = 0;
    for (int i = 0; i < cs; ++i) s += lh[threadIdx.x * cs + i];
    csum[threadIdx.x] = s;
    __syncthreads();
    if (threadIdx.x == 0) {
        uint32_t before = 0; int b = 0; uint32_t rem = 1;
        for (int c = NTHR - 1; c >= 0; --c) {
            if (before + csum[c] >= k) {
                for (int bb = c * cs + cs - 1; bb >= c * cs; --bb) {
                    uint32_t cnt = lh[bb];
                    if (before + cnt >= k) { b = bb; rem = k - before; break; }
                    before += cnt;
                }
                break;
            }
            before += csum[c];
        }
        sb3 = (uint32_t)b; sj = rem;
        uint32_t t = (ws[SEL_OFF + 0] << 20) | (ws[SEL_OFF + 2] << 9) | (uint32_t)b;
        ws[SEL_OFF + 4] = t;
    }
    __syncthreads();
    uint32_t b3 = sb3;
    uint32_t gc = ws[SEL_OFF + 6];
    uint32_t m_all = gc < GATHER_CAP ? gc : GATHER_CAP;
    for (uint32_t i = threadIdx.x; i < m_all; i += NTHR) {
        if (ws[GLOW_OFF + i] == b3) {
            uint32_t p = atomicAdd(&tieCnt, 1u);
            if (p < KEEP_CAP) tieIdx[p] = ws[GIDX_OFF + i];
        }
    }
    __syncthreads();
    if (threadIdx.x == 0) {
        int m = (int)(tieCnt < KEEP_CAP ? tieCnt : KEEP_CAP);
        // insertion sort ascending (m is tiny: expected O(1))
        for (int a = 1; a < m; ++a) {
            uint32_t v = tieIdx[a]; int bp = a - 1;
            while (bp >= 0 && tieIdx[bp] > v) { tieIdx[bp + 1] = tieIdx[bp]; --bp; }
            tieIdx[bp + 1] = v;
        }
        uint32_t j = sj;
        if (j > (uint32_t)m) j = (uint32_t)m;  // safety (shouldn't trigger)
        for (uint32_t q = 0; q < j; ++q) ws[KEEP_OFF + q] = tieIdx[q];
        ws[SEL_OFF + 5] = j;
    }
}

// ---------------- output pass -----------------------------------------------
__device__ __forceinline__ uint32_t keep_val(uint32_t v, long long idx, uint32_t t,
                                             uint32_t j, const uint32_t* __restrict__ ws) {
    uint32_t u = v & 0x7fffffffu;
    if (u > t) return v;
    if (u == t) {
        uint32_t id = (uint32_t)idx;
        for (uint32_t q = 0; q < j; ++q)
            if (ws[KEEP_OFF + q] == id) return v;
    }
    return 0u;
}

__global__ void output_kernel(const uint32_t* __restrict__ x, uint32_t* __restrict__ out,
                              long long n, const uint32_t* __restrict__ ws) {
    uint32_t t = ws[SEL_OFF + 4];
    uint32_t j = ws[SEL_OFF + 5];
    long long n4 = n >> 2;
    const uint4* xv = (const uint4*)x;
    uint4* ov = (uint4*)out;
    long long stride = (long long)gridDim.x * NTHR;
    for (long long i = (long long)blockIdx.x * NTHR + threadIdx.x; i < n4; i += stride) {
        uint4 v = xv[i];
        long long base = i << 2;
        uint4 o;
        o.x = keep_val(v.x, base + 0, t, j, ws);
        o.y = keep_val(v.y, base + 1, t, j, ws);
        o.z = keep_val(v.z, base + 2, t, j, ws);
        o.w = keep_val(v.w, base + 3, t, j, ws);
        ov[i] = o;
    }
    if (blockIdx.x == 0 && threadIdx.x < (int)(n & 3)) {
        long long idx = (n4 << 2) + threadIdx.x;
        out[idx] = keep_val(x[idx], idx, t, j, ws);
    }
}

extern "C" void kernel_launch(void* const* d_in, const int* in_sizes, int n_in,
                              void* d_out, int out_size, void* d_ws, size_t ws_size,
                              hipStream_t stream) {
    const uint32_t* x = (const uint32_t*)d_in[0];
    uint32_t* out = (uint32_t*)d_out;
    uint32_t* ws = (uint32_t*)d_ws;
    long long n = (long long)in_sizes[0];

    const double ratio = 0.5;  // SPARSE_COMPRESSION_RATIO
    long long k = (long long)((double)n * (1.0 - ratio));
    if (k < 1) k = 1;          // degenerate guard (not hit for this config)
    if (k > n) k = n;

    zero_ws_kernel<<<(WS_WORDS + NTHR - 1) / NTHR, NTHR, 0, stream>>>(ws);
    hist1_kernel<<<NBLK, NTHR, 0, stream>>>(x, n, ws);
    select12_kernel<<<1, NTHR, 0, stream>>>(ws, H1_OFF, 2048, -1, (uint32_t)k, 0);
    hist2_kernel<<<NBLK, NTHR, 0, stream>>>(x, n, ws);
    select12_kernel<<<1, NTHR, 0, stream>>>(ws, H2_OFF, 2048, 1, 0u, 2);
    hist3_kernel<<<NBLK, NTHR, 0, stream>>>(x, n, ws);
    select3_kernel<<<1, NTHR, 0, stream>>>(ws);
    output_kernel<<<NBLK, NTHR, 0, stream>>>(x, out, n, ws);
}

// Round 2
// 178.871 us; speedup vs baseline: 1.1833x; 1.1833x over previous
//
#include <hip/hip_runtime.h>
#include <stdint.h>

// ----------------------------------------------------------------------------
// SparseKVCache: keep top-k by |x| (k = n/2), zero the rest. Exact.
// Strategy: sampled bracket (prob-safe, ~8 sigma) -> one full-data pass that
// exactly counts above-bracket and gathers in-bracket (value,index) pairs ->
// exact select on the small candidate set (stable ties: smallest indices) ->
// output pass. All atomics produce order-independent results => deterministic.
// ----------------------------------------------------------------------------

#define NTHR 256

// ---- ws layout (uint32 words) ----
#define SH_OFF    0           // 8192-bin histogram (samples; reused for cands)
#define SCL_OFF   8192        // scalars, 16 words:
//  [0]=bLo [1]=bHi [2]=shift1 [3]=spanBase [4]=cntHi [5]=gCount
//  [6]=base2 [7]=rem2 [8]=c3 [9]=t [10]=j
#define KEEP_OFF  8208        // kept tie indices
#define KEEP_CAP  1024
#define L3_OFF    9232        // level-3 pairs (uint2), offset even => 8B aligned
#define L3_CAP    65536
#define PAIRS_OFF 140304      // candidate pairs (uint2)
#define PAIRS_CAP 4194304     // 4M pairs = 32 MB
#define ZERO_WORDS 8208       // SH + scalars

#define SSTRIDE 64            // sample every 64th element (256 B)

__global__ void zero_ws_kernel(uint32_t* __restrict__ ws) {
    int i = blockIdx.x * blockDim.x + threadIdx.x;
    if (i < ZERO_WORDS) ws[i] = 0;
}

// ---- sample histogram: bits 30..18 of |x| over strided samples --------------
__global__ void sample_hist_kernel(const uint32_t* __restrict__ x, long long n,
                                   uint32_t* __restrict__ ws) {
    __shared__ uint32_t lh[8192];
    for (int i = threadIdx.x; i < 8192; i += NTHR) lh[i] = 0;
    __syncthreads();
    long long S = n / SSTRIDE;
    long long T = (long long)gridDim.x * NTHR;
    for (long long i = (long long)blockIdx.x * NTHR + threadIdx.x; i < S; i += T) {
        uint32_t u = x[i * SSTRIDE] & 0x7fffffffu;
        atomicAdd(&lh[u >> 18], 1u);
    }
    __syncthreads();
    for (int i = threadIdx.x; i < 8192; i += NTHR)
        if (lh[i]) atomicAdd(&ws[SH_OFF + i], lh[i]);
}

// ---- bracket select from sample histogram -----------------------------------
// bHi = largest bin with inclusive-from-top sample count >= ks-M
// bLo = 1 + largest bin with exclusive-from-top sample count >= ks+M
__global__ void sel_bracket_kernel(uint32_t* __restrict__ ws,
                                   uint32_t ksmM, uint32_t kspM) {
    __shared__ uint32_t lh[8192];
    __shared__ uint32_t csum[NTHR];
    __shared__ uint32_t cpre[NTHR];
    __shared__ int sBHi, sB1;
    for (int i = threadIdx.x; i < 8192; i += NTHR) lh[i] = ws[SH_OFF + i];
    if (threadIdx.x == 0) { sBHi = -1; sB1 = -1; }
    __syncthreads();
    // re-zero global hist for reuse by cand_hist2
    for (int i = threadIdx.x; i < 8192; i += NTHR) ws[SH_OFF + i] = 0;
    // chunk sums (32 bins per thread)
    uint32_t s = 0;
    for (int i = 0; i < 32; ++i) s += lh[threadIdx.x * 32 + i];
    csum[threadIdx.x] = s;
    __syncthreads();
    if (threadIdx.x == 0) {
        uint32_t run = 0;
        for (int c = NTHR - 1; c >= 0; --c) { cpre[c] = run; run += csum[c]; }
    }
    __syncthreads();
    {
        int c = threadIdx.x;
        int hitHi = -1, hitB1 = -1;
        uint32_t excl = cpre[c];
        for (int bb = c * 32 + 31; bb >= c * 32; --bb) {
            uint32_t cnt = lh[bb];
            uint32_t incl = excl + cnt;
            if (hitHi < 0 && incl >= ksmM) hitHi = bb;
            if (hitB1 < 0 && excl >= kspM) hitB1 = bb;
            excl = incl;
        }
        if (hitHi >= 0) atomicMax(&sBHi, hitHi);
        if (hitB1 >= 0) atomicMax(&sB1, hitB1);
    }
    __syncthreads();
    if (threadIdx.x == 0) {
        int bHi = sBHi < 0 ? 0 : sBHi;
        int bLo = sB1 + 1;
        if (bLo > bHi) bLo = bHi;
        if (bLo < 0) bLo = 0;
        int span = bHi - bLo + 1;
        int clog = 0; while ((1 << clog) < span) ++clog;
        int spanBits = 18 + clog;
        int shift1 = spanBits > 12 ? spanBits - 12 : 0;
        ws[SCL_OFF + 0] = (uint32_t)bLo;
        ws[SCL_OFF + 1] = (uint32_t)bHi;
        ws[SCL_OFF + 2] = (uint32_t)shift1;
        ws[SCL_OFF + 3] = ((uint32_t)bLo) << 18;
    }
}

// ---- full pass: exact cntHi + gather bracket (value,index) pairs ------------
#define GC_CAP 2048
__global__ void gather_kernel(const uint32_t* __restrict__ x, long long n,
                              uint32_t* __restrict__ ws) {
    __shared__ uint2 stage[GC_CAP];
    __shared__ uint32_t cnt, sHi, base;
    uint32_t bLo = ws[SCL_OFF + 0], bHi = ws[SCL_OFF + 1];
    if (threadIdx.x == 0) { cnt = 0; sHi = 0; }
    __syncthreads();
    uint32_t myHi = 0;
    long long n4 = n >> 2;
    const uint4* xv = (const uint4*)x;
    long long stride = (long long)gridDim.x * NTHR;
    for (long long i = (long long)blockIdx.x * NTHR + threadIdx.x; i < n4; i += stride) {
        uint4 v = xv[i];
        uint32_t base4 = (uint32_t)(i << 2);
        uint32_t u, b;
        u = v.x & 0x7fffffffu; b = u >> 18;
        if (b > bHi) ++myHi;
        else if (b >= bLo) { uint32_t p = atomicAdd(&cnt, 1u); if (p < GC_CAP) stage[p] = make_uint2(u, base4 + 0); }
        u = v.y & 0x7fffffffu; b = u >> 18;
        if (b > bHi) ++myHi;
        else if (b >= bLo) { uint32_t p = atomicAdd(&cnt, 1u); if (p < GC_CAP) stage[p] = make_uint2(u, base4 + 1); }
        u = v.z & 0x7fffffffu; b = u >> 18;
        if (b > bHi) ++myHi;
        else if (b >= bLo) { uint32_t p = atomicAdd(&cnt, 1u); if (p < GC_CAP) stage[p] = make_uint2(u, base4 + 2); }
        u = v.w & 0x7fffffffu; b = u >> 18;
        if (b > bHi) ++myHi;
        else if (b >= bLo) { uint32_t p = atomicAdd(&cnt, 1u); if (p < GC_CAP) stage[p] = make_uint2(u, base4 + 3); }
    }
    if (blockIdx.x == 0 && threadIdx.x < (int)(n & 3)) {
        long long idx = (n4 << 2) + threadIdx.x;
        uint32_t u = x[idx] & 0x7fffffffu;
        uint32_t b = u >> 18;
        if (b > bHi) ++myHi;
        else if (b >= bLo) { uint32_t p = atomicAdd(&cnt, 1u); if (p < GC_CAP) stage[p] = make_uint2(u, (uint32_t)idx); }
    }
    if (myHi) atomicAdd(&sHi, myHi);
    __syncthreads();
    if (threadIdx.x == 0) {
        uint32_t c = cnt < GC_CAP ? cnt : GC_CAP;
        cnt = c;
        base = atomicAdd(&ws[SCL_OFF + 5], c);
        if (sHi) atomicAdd(&ws[SCL_OFF + 4], sHi);
    }
    __syncthreads();
    uint2* pairs = (uint2*)(ws + PAIRS_OFF);
    uint32_t c = cnt, b0 = base;
    for (uint32_t i = threadIdx.x; i < c; i += NTHR)
        if (b0 + i < PAIRS_CAP) pairs[b0 + i] = stage[i];
}

// ---- candidate histogram (4096 bins over bracket range) ---------------------
__global__ void cand_hist2_kernel(uint32_t* __restrict__ ws) {
    __shared__ uint32_t lh[4096];
    uint32_t G = ws[SCL_OFF + 5]; if (G > PAIRS_CAP) G = PAIRS_CAP;
    uint32_t spanBase = ws[SCL_OFF + 3], shift1 = ws[SCL_OFF + 2];
    for (int i = threadIdx.x; i < 4096; i += NTHR) lh[i] = 0;
    __syncthreads();
    const uint2* pairs = (const uint2*)(ws + PAIRS_OFF);
    uint32_t stride = gridDim.x * NTHR;
    for (uint32_t i = blockIdx.x * NTHR + threadIdx.x; i < G; i += stride) {
        uint32_t u = pairs[i].x;
        atomicAdd(&lh[((u - spanBase) >> shift1) & 4095u], 1u);
    }
    __syncthreads();
    for (int i = threadIdx.x; i < 4096; i += NTHR)
        if (lh[i]) atomicAdd(&ws[SH_OFF + i], lh[i]);
}

// ---- select level-2 bin ------------------------------------------------------
__global__ void cand_sel1_kernel(uint32_t* __restrict__ ws, uint32_t k) {
    __shared__ uint32_t lh[4096];
    __shared__ uint32_t csum[NTHR];
    __shared__ uint32_t cpre[NTHR];
    for (int i = threadIdx.x; i < 4096; i += NTHR) lh[i] = ws[SH_OFF + i];
    __syncthreads();
    uint32_t kp = k - ws[SCL_OFF + 4];   // k' among candidates
    uint32_t s = 0;
    for (int i = 0; i < 16; ++i) s += lh[threadIdx.x * 16 + i];
    csum[threadIdx.x] = s;
    __syncthreads();
    if (threadIdx.x == 0) {
        uint32_t run = 0;
        for (int c = NTHR - 1; c >= 0; --c) { cpre[c] = run; run += csum[c]; }
    }
    __syncthreads();
    if (cpre[threadIdx.x] < kp && kp <= cpre[threadIdx.x] + csum[threadIdx.x]) {
        uint32_t excl = cpre[threadIdx.x];
        for (int bb = threadIdx.x * 16 + 15; bb >= threadIdx.x * 16; --bb) {
            uint32_t cnt = lh[bb];
            if (excl + cnt >= kp) {
                ws[SCL_OFF + 6] = ws[SCL_OFF + 3] + (((uint32_t)bb) << ws[SCL_OFF + 2]);
                ws[SCL_OFF + 7] = kp - excl;
                break;
            }
            excl += cnt;
        }
    }
}

// ---- gather level-3 set (candidates within selected level-2 bin) ------------
__global__ void cand_gather2_kernel(uint32_t* __restrict__ ws) {
    uint32_t G = ws[SCL_OFF + 5]; if (G > PAIRS_CAP) G = PAIRS_CAP;
    uint32_t base2 = ws[SCL_OFF + 6];
    uint32_t width = 1u << ws[SCL_OFF + 2];
    const uint2* pairs = (const uint2*)(ws + PAIRS_OFF);
    uint2* l3 = (uint2*)(ws + L3_OFF);
    uint32_t stride = gridDim.x * NTHR;
    for (uint32_t i = blockIdx.x * NTHR + threadIdx.x; i < G; i += stride) {
        uint2 pr = pairs[i];
        if (pr.x - base2 < width) {
            uint32_t p = atomicAdd(&ws[SCL_OFF + 8], 1u);
            if (p < L3_CAP) l3[p] = pr;
        }
    }
}

// ---- final: exact threshold t, tie count j, keep-list (smallest indices) ----
__global__ void final_sel_kernel(uint32_t* __restrict__ ws) {
    __shared__ uint32_t lh[4096];
    __shared__ uint32_t csum[NTHR];
    __shared__ uint32_t cpre[NTHR];
    __shared__ uint32_t tieIdx[KEEP_CAP];
    __shared__ uint32_t tieCnt;
    __shared__ uint32_t sT, sJ;
    uint32_t c3 = ws[SCL_OFF + 8]; if (c3 > L3_CAP) c3 = L3_CAP;
    uint32_t base2 = ws[SCL_OFF + 6];
    uint32_t rem2  = ws[SCL_OFF + 7];
    for (int i = threadIdx.x; i < 4096; i += NTHR) lh[i] = 0;
    if (threadIdx.x == 0) tieCnt = 0;
    __syncthreads();
    const uint2* l3 = (const uint2*)(ws + L3_OFF);
    for (uint32_t i = threadIdx.x; i < c3; i += NTHR)
        atomicAdd(&lh[(l3[i].x - base2) & 4095u], 1u);
    __syncthreads();
    uint32_t s = 0;
    for (int i = 0; i < 16; ++i) s += lh[threadIdx.x * 16 + i];
    csum[threadIdx.x] = s;
    __syncthreads();
    if (threadIdx.x == 0) {
        uint32_t run = 0;
        for (int c = NTHR - 1; c >= 0; --c) { cpre[c] = run; run += csum[c]; }
    }
    __syncthreads();
    if (cpre[threadIdx.x] < rem2 && rem2 <= cpre[threadIdx.x] + csum[threadIdx.x]) {
        uint32_t excl = cpre[threadIdx.x];
        for (int bb = threadIdx.x * 16 + 15; bb >= threadIdx.x * 16; --bb) {
            uint32_t cnt = lh[bb];
            if (excl + cnt >= rem2) { sT = base2 + (uint32_t)bb; sJ = rem2 - excl; break; }
            excl += cnt;
        }
    }
    __syncthreads();
    uint32_t t = sT;
    for (uint32_t i = threadIdx.x; i < c3; i += NTHR) {
        uint2 pr = l3[i];
        if (pr.x == t) {
            uint32_t p = atomicAdd(&tieCnt, 1u);
            if (p < KEEP_CAP) tieIdx[p] = pr.y;
        }
    }
    __syncthreads();
    if (threadIdx.x == 0) {
        int m = (int)(tieCnt < KEEP_CAP ? tieCnt : KEEP_CAP);
        for (int a = 1; a < m; ++a) {  // tiny insertion sort
            uint32_t v = tieIdx[a]; int bp = a - 1;
            while (bp >= 0 && tieIdx[bp] > v) { tieIdx[bp + 1] = tieIdx[bp]; --bp; }
            tieIdx[bp + 1] = v;
        }
        uint32_t j = sJ;
        if (j > (uint32_t)m) j = (uint32_t)m;
        for (uint32_t q = 0; q < j; ++q) ws[KEEP_OFF + q] = tieIdx[q];
        ws[SCL_OFF + 9]  = t;
        ws[SCL_OFF + 10] = j;
    }
}

// ---- output pass ------------------------------------------------------------
__device__ __forceinline__ uint32_t keep_val(uint32_t v, uint32_t idx, uint32_t t,
                                             uint32_t j, const uint32_t* __restrict__ ws) {
    uint32_t u = v & 0x7fffffffu;
    if (u > t) return v;
    if (u == t) {
        for (uint32_t q = 0; q < j; ++q)
            if (ws[KEEP_OFF + q] == idx) return v;
    }
    return 0u;
}

__global__ void output_kernel(const uint32_t* __restrict__ x, uint32_t* __restrict__ out,
                              long long n, const uint32_t* __restrict__ ws) {
    uint32_t t = ws[SCL_OFF + 9];
    uint32_t j = ws[SCL_OFF + 10];
    long long n4 = n >> 2;
    const uint4* xv = (const uint4*)x;
    uint4* ov = (uint4*)out;
    long long stride = (long long)gridDim.x * NTHR;
    for (long long i = (long long)blockIdx.x * NTHR + threadIdx.x; i < n4; i += stride) {
        uint4 v = xv[i];
        uint32_t base4 = (uint32_t)(i << 2);
        uint4 o;
        o.x = keep_val(v.x, base4 + 0, t, j, ws);
        o.y = keep_val(v.y, base4 + 1, t, j, ws);
        o.z = keep_val(v.z, base4 + 2, t, j, ws);
        o.w = keep_val(v.w, base4 + 3, t, j, ws);
        ov[i] = o;
    }
    if (blockIdx.x == 0 && threadIdx.x < (int)(n & 3)) {
        long long idx = (n4 << 2) + threadIdx.x;
        out[idx] = keep_val(x[idx], (uint32_t)idx, t, j, ws);
    }
}

extern "C" void kernel_launch(void* const* d_in, const int* in_sizes, int n_in,
                              void* d_out, int out_size, void* d_ws, size_t ws_size,
                              hipStream_t stream) {
    const uint32_t* x = (const uint32_t*)d_in[0];
    uint32_t* out = (uint32_t*)d_out;
    uint32_t* ws = (uint32_t*)d_ws;
    long long n = (long long)in_sizes[0];

    const double ratio = 0.5;  // SPARSE_COMPRESSION_RATIO
    long long k = (long long)((double)n * (1.0 - ratio));
    if (k < 1) k = 1;
    if (k > n) k = n;

    long long S = n / SSTRIDE;
    long long ks = (long long)((double)k * ((double)S / (double)n));
    const long long M = 3000;  // ~8 sigma at S=524288
    uint32_t ksmM = (uint32_t)((ks - M) < 1 ? 1 : (ks - M));
    uint32_t kspM = (uint32_t)((ks + M) > S ? S : (ks + M));

    zero_ws_kernel<<<(ZERO_WORDS + NTHR - 1) / NTHR, NTHR, 0, stream>>>(ws);
    sample_hist_kernel<<<512, NTHR, 0, stream>>>(x, n, ws);
    sel_bracket_kernel<<<1, NTHR, 0, stream>>>(ws, ksmM, kspM);
    gather_kernel<<<2048, NTHR, 0, stream>>>(x, n, ws);
    cand_hist2_kernel<<<256, NTHR, 0, stream>>>(ws);
    cand_sel1_kernel<<<1, NTHR, 0, stream>>>(ws, (uint32_t)k);
    cand_gather2_kernel<<<256, NTHR, 0, stream>>>(ws);
    final_sel_kernel<<<1, NTHR, 0, stream>>>(ws);
    output_kernel<<<2048, NTHR, 0, stream>>>(x, out, n, ws);
}

// Round 3
// 154.679 us; speedup vs baseline: 1.3683x; 1.1564x over previous
//
#include <hip/hip_runtime.h>
#include <stdint.h>

// ----------------------------------------------------------------------------
// SparseKVCache: keep top-k by |x| (k = n/2), zero the rest. Exact.
// R3: sampled bracket -> ONE fused full pass (write definite outputs, count
// above-bracket exactly, gather in-bracket (value,index) pairs) -> exact
// select on candidate set (multi-block, redundant per-block selection) ->
// scatter-fixup of kept candidates. Stable ties = smallest indices, via
// "kept tie <=> idx <= j-th smallest tie index". Deterministic.
// ----------------------------------------------------------------------------

#define NTHR 256
#define MASK31 0x7fffffffu

// ---- ws layout (uint32 words) ----
#define SH_OFF    0           // 8192-bin sample histogram (bits 30..18)
#define SH_BINS   8192
#define CH_OFF    8192        // 4096-bin candidate histogram
#define CH_BINS   4096
#define SCL_OFF   12288       // scalars:
//  [0]=bLo [1]=bHi [2]=shift1 [3]=spanBase [4]=cntHi [5]=gCount
//  [6]=base2 [7]=rem2 [8]=c3
#define L3_OFF    12320       // level-3 pairs (uint2), even word => 8B aligned
#define L3_CAP    4096
#define PAIRS_OFF (L3_OFF + 2 * L3_CAP)   // 20512, even => 8B aligned
#define PAIRS_CAP 4194304                  // 4M pairs = 32 MB
#define ZERO_WORDS (SCL_OFF + 32)

#define GC_CAP    4096        // per-block LDS staging for gathered pairs
#define TIE_CAP   1024

__global__ void zero_ws_kernel(uint32_t* __restrict__ ws) {
    int i = blockIdx.x * blockDim.x + threadIdx.x;
    if (i < ZERO_WORDS) ws[i] = 0;
}

// ---- sample histogram: one uint4 (4 samples) per 32 uint4s (512 B) ---------
__global__ void sample_hist_kernel(const uint4* __restrict__ xv, long long n4,
                                   uint32_t* __restrict__ ws) {
    __shared__ uint32_t lh[SH_BINS];
    for (int i = threadIdx.x; i < SH_BINS; i += NTHR) lh[i] = 0;
    __syncthreads();
    long long S4 = n4 >> 5;
    long long T = (long long)gridDim.x * NTHR;
    for (long long s = (long long)blockIdx.x * NTHR + threadIdx.x; s < S4; s += T) {
        uint4 v = xv[s << 5];
        atomicAdd(&lh[(v.x & MASK31) >> 18], 1u);
        atomicAdd(&lh[(v.y & MASK31) >> 18], 1u);
        atomicAdd(&lh[(v.z & MASK31) >> 18], 1u);
        atomicAdd(&lh[(v.w & MASK31) >> 18], 1u);
    }
    __syncthreads();
    for (int i = threadIdx.x; i < SH_BINS; i += NTHR)
        if (lh[i]) atomicAdd(&ws[SH_OFF + i], lh[i]);
}

// ---- bracket select from sample histogram -----------------------------------
__global__ void sel_bracket_kernel(uint32_t* __restrict__ ws,
                                   uint32_t ksmM, uint32_t kspM) {
    __shared__ uint32_t lh[SH_BINS];
    __shared__ uint32_t csum[NTHR];
    __shared__ uint32_t cpre[NTHR];
    __shared__ int sBHi, sB1;
    for (int i = threadIdx.x; i < SH_BINS; i += NTHR) lh[i] = ws[SH_OFF + i];
    if (threadIdx.x == 0) { sBHi = -1; sB1 = -1; }
    __syncthreads();
    uint32_t s = 0;
    for (int i = 0; i < 32; ++i) s += lh[threadIdx.x * 32 + i];
    csum[threadIdx.x] = s;
    __syncthreads();
    if (threadIdx.x == 0) {
        uint32_t run = 0;
        for (int c = NTHR - 1; c >= 0; --c) { cpre[c] = run; run += csum[c]; }
    }
    __syncthreads();
    {
        int c = threadIdx.x;
        int hitHi = -1, hitB1 = -1;
        uint32_t excl = cpre[c];
        for (int bb = c * 32 + 31; bb >= c * 32; --bb) {
            uint32_t cnt = lh[bb];
            uint32_t incl = excl + cnt;
            if (hitHi < 0 && incl >= ksmM) hitHi = bb;
            if (hitB1 < 0 && excl >= kspM) hitB1 = bb;
            excl = incl;
        }
        if (hitHi >= 0) atomicMax(&sBHi, hitHi);
        if (hitB1 >= 0) atomicMax(&sB1, hitB1);
    }
    __syncthreads();
    if (threadIdx.x == 0) {
        int bHi = sBHi < 0 ? 0 : sBHi;
        int bLo = sB1 + 1;
        if (bLo > bHi) bLo = bHi;
        if (bLo < 0) bLo = 0;
        int span = bHi - bLo + 1;
        int clog = 0; while ((1 << clog) < span) ++clog;
        int spanBits = 18 + clog;
        int shift1 = spanBits > 12 ? spanBits - 12 : 0;
        ws[SCL_OFF + 0] = (uint32_t)bLo;
        ws[SCL_OFF + 1] = (uint32_t)bHi;
        ws[SCL_OFF + 2] = (uint32_t)shift1;
        ws[SCL_OFF + 3] = ((uint32_t)bLo) << 18;
    }
}

// ---- fused full pass: write definite out, exact cntHi, gather bracket ------
__global__ void fused_main_kernel(const uint32_t* __restrict__ x,
                                  uint32_t* __restrict__ out, long long n,
                                  uint32_t* __restrict__ ws) {
    __shared__ uint2 stage[GC_CAP];
    __shared__ uint32_t cnt, sHi, base;
    uint32_t bLo = ws[SCL_OFF + 0], bHi = ws[SCL_OFF + 1];
    if (threadIdx.x == 0) { cnt = 0; sHi = 0; }
    __syncthreads();
    uint32_t myHi = 0;
    long long n4 = n >> 2;
    const uint4* xv = (const uint4*)x;
    uint4* ov = (uint4*)out;
    long long stride = (long long)gridDim.x * NTHR;
    for (long long i = (long long)blockIdx.x * NTHR + threadIdx.x; i < n4; i += stride) {
        uint4 v = xv[i];
        uint32_t base4 = (uint32_t)(i << 2);
        uint4 o;
        uint32_t u, b;
        u = v.x & MASK31; b = u >> 18;
        if (b > bHi) { o.x = v.x; ++myHi; }
        else { o.x = 0u; if (b >= bLo) { uint32_t p = atomicAdd(&cnt, 1u); if (p < GC_CAP) stage[p] = make_uint2(v.x, base4 + 0); } }
        u = v.y & MASK31; b = u >> 18;
        if (b > bHi) { o.y = v.y; ++myHi; }
        else { o.y = 0u; if (b >= bLo) { uint32_t p = atomicAdd(&cnt, 1u); if (p < GC_CAP) stage[p] = make_uint2(v.y, base4 + 1); } }
        u = v.z & MASK31; b = u >> 18;
        if (b > bHi) { o.z = v.z; ++myHi; }
        else { o.z = 0u; if (b >= bLo) { uint32_t p = atomicAdd(&cnt, 1u); if (p < GC_CAP) stage[p] = make_uint2(v.z, base4 + 2); } }
        u = v.w & MASK31; b = u >> 18;
        if (b > bHi) { o.w = v.w; ++myHi; }
        else { o.w = 0u; if (b >= bLo) { uint32_t p = atomicAdd(&cnt, 1u); if (p < GC_CAP) stage[p] = make_uint2(v.w, base4 + 3); } }
        ov[i] = o;
    }
    if (blockIdx.x == 0 && threadIdx.x < (int)(n & 3)) {
        long long idx = (n4 << 2) + threadIdx.x;
        uint32_t v = x[idx];
        uint32_t u = v & MASK31, b = u >> 18;
        uint32_t o = 0u;
        if (b > bHi) { o = v; ++myHi; }
        else if (b >= bLo) { uint32_t p = atomicAdd(&cnt, 1u); if (p < GC_CAP) stage[p] = make_uint2(v, (uint32_t)idx); }
        out[idx] = o;
    }
    if (myHi) atomicAdd(&sHi, myHi);
    __syncthreads();
    if (threadIdx.x == 0) {
        uint32_t c = cnt < GC_CAP ? cnt : GC_CAP;
        cnt = c;
        base = atomicAdd(&ws[SCL_OFF + 5], c);
        if (sHi) atomicAdd(&ws[SCL_OFF + 4], sHi);
    }
    __syncthreads();
    uint2* pairs = (uint2*)(ws + PAIRS_OFF);
    uint32_t c = cnt, b0 = base;
    for (uint32_t q = threadIdx.x; q < c; q += NTHR)
        if (b0 + q < PAIRS_CAP) pairs[b0 + q] = stage[q];
}

// ---- candidate histogram ----------------------------------------------------
__global__ void cand_hist_kernel(uint32_t* __restrict__ ws) {
    __shared__ uint32_t lh[CH_BINS];
    uint32_t G = ws[SCL_OFF + 5]; if (G > PAIRS_CAP) G = PAIRS_CAP;
    uint32_t spanBase = ws[SCL_OFF + 3], shift1 = ws[SCL_OFF + 2];
    for (int i = threadIdx.x; i < CH_BINS; i += NTHR) lh[i] = 0;
    __syncthreads();
    const uint2* pairs = (const uint2*)(ws + PAIRS_OFF);
    uint32_t stride = gridDim.x * NTHR;
    for (uint32_t i = blockIdx.x * NTHR + threadIdx.x; i < G; i += stride) {
        uint32_t u = pairs[i].x & MASK31;
        atomicAdd(&lh[((u - spanBase) >> shift1) & (CH_BINS - 1)], 1u);
    }
    __syncthreads();
    for (int i = threadIdx.x; i < CH_BINS; i += NTHR)
        if (lh[i]) atomicAdd(&ws[CH_OFF + i], lh[i]);
}

// ---- level-2 select (redundant per block) + gather in-bin pairs -------------
__global__ void sel_gather_kernel(uint32_t* __restrict__ ws, uint32_t k) {
    __shared__ uint32_t lh[CH_BINS];
    __shared__ uint32_t csum[NTHR];
    __shared__ uint32_t cpre[NTHR];
    __shared__ uint32_t sBase2, sRem2;
    for (int i = threadIdx.x; i < CH_BINS; i += NTHR) lh[i] = ws[CH_OFF + i];
    __syncthreads();
    uint32_t kp = k - ws[SCL_OFF + 4];
    uint32_t s = 0;
    for (int i = 0; i < 16; ++i) s += lh[threadIdx.x * 16 + i];
    csum[threadIdx.x] = s;
    __syncthreads();
    if (threadIdx.x == 0) {
        uint32_t run = 0;
        for (int c = NTHR - 1; c >= 0; --c) { cpre[c] = run; run += csum[c]; }
    }
    __syncthreads();
    if (cpre[threadIdx.x] < kp && kp <= cpre[threadIdx.x] + csum[threadIdx.x]) {
        uint32_t excl = cpre[threadIdx.x];
        for (int bb = threadIdx.x * 16 + 15; bb >= threadIdx.x * 16; --bb) {
            uint32_t cnt = lh[bb];
            if (excl + cnt >= kp) {
                sBase2 = ws[SCL_OFF + 3] + (((uint32_t)bb) << ws[SCL_OFF + 2]);
                sRem2 = kp - excl;
                break;
            }
            excl += cnt;
        }
    }
    __syncthreads();
    if (threadIdx.x == 0) { ws[SCL_OFF + 6] = sBase2; ws[SCL_OFF + 7] = sRem2; }
    uint32_t base2 = sBase2;
    uint32_t width = 1u << ws[SCL_OFF + 2];
    uint32_t G = ws[SCL_OFF + 5]; if (G > PAIRS_CAP) G = PAIRS_CAP;
    const uint2* pairs = (const uint2*)(ws + PAIRS_OFF);
    uint2* l3 = (uint2*)(ws + L3_OFF);
    uint32_t stride = gridDim.x * NTHR;
    for (uint32_t i = blockIdx.x * NTHR + threadIdx.x; i < G; i += stride) {
        uint2 pr = pairs[i];
        uint32_t u = pr.x & MASK31;
        if (u - base2 < width) {
            uint32_t p = atomicAdd(&ws[SCL_OFF + 8], 1u);
            if (p < L3_CAP) l3[p] = pr;
        }
    }
}

// ---- final select (redundant per block) + scatter-fixup kept candidates ----
__global__ void final_fixup_kernel(uint32_t* __restrict__ ws,
                                   uint32_t* __restrict__ out) {
    __shared__ uint32_t lh[CH_BINS];
    __shared__ uint32_t csum[NTHR];
    __shared__ uint32_t cpre[NTHR];
    __shared__ uint32_t tieIdx[TIE_CAP];
    __shared__ uint32_t tieCnt, sT, sJ, sTieMax;
    uint32_t c3 = ws[SCL_OFF + 8]; if (c3 > L3_CAP) c3 = L3_CAP;
    uint32_t base2 = ws[SCL_OFF + 6], rem2 = ws[SCL_OFF + 7];
    for (int i = threadIdx.x; i < CH_BINS; i += NTHR) lh[i] = 0;
    if (threadIdx.x == 0) tieCnt = 0;
    __syncthreads();
    const uint2* l3 = (const uint2*)(ws + L3_OFF);
    for (uint32_t i = threadIdx.x; i < c3; i += NTHR) {
        uint32_t u = l3[i].x & MASK31;
        atomicAdd(&lh[(u - base2) & (CH_BINS - 1)], 1u);
    }
    __syncthreads();
    uint32_t s = 0;
    for (int i = 0; i < 16; ++i) s += lh[threadIdx.x * 16 + i];
    csum[threadIdx.x] = s;
    __syncthreads();
    if (threadIdx.x == 0) {
        uint32_t run = 0;
        for (int c = NTHR - 1; c >= 0; --c) { cpre[c] = run; run += csum[c]; }
    }
    __syncthreads();
    if (cpre[threadIdx.x] < rem2 && rem2 <= cpre[threadIdx.x] + csum[threadIdx.x]) {
        uint32_t excl = cpre[threadIdx.x];
        for (int bb = threadIdx.x * 16 + 15; bb >= threadIdx.x * 16; --bb) {
            uint32_t cnt = lh[bb];
            if (excl + cnt >= rem2) { sT = base2 + (uint32_t)bb; sJ = rem2 - excl; break; }
            excl += cnt;
        }
    }
    __syncthreads();
    uint32_t t = sT;
    for (uint32_t i = threadIdx.x; i < c3; i += NTHR) {
        uint2 pr = l3[i];
        if ((pr.x & MASK31) == t) {
            uint32_t p = atomicAdd(&tieCnt, 1u);
            if (p < TIE_CAP) tieIdx[p] = pr.y;
        }
    }
    __syncthreads();
    if (threadIdx.x == 0) {
        uint32_t m = tieCnt < TIE_CAP ? tieCnt : TIE_CAP;
        for (uint32_t a = 1; a < m; ++a) {   // tiny insertion sort
            uint32_t v = tieIdx[a]; int bp = (int)a - 1;
            while (bp >= 0 && tieIdx[bp] > v) { tieIdx[bp + 1] = tieIdx[bp]; --bp; }
            tieIdx[bp + 1] = v;
        }
        uint32_t j = sJ;
        if (j > m) j = m;
        sJ = j;
        sTieMax = (j > 0) ? tieIdx[j - 1] : 0u;
    }
    __syncthreads();
    uint32_t j = sJ, tieMax = sTieMax;
    uint32_t G = ws[SCL_OFF + 5]; if (G > PAIRS_CAP) G = PAIRS_CAP;
    const uint2* pairs = (const uint2*)(ws + PAIRS_OFF);
    uint32_t stride = gridDim.x * NTHR;
    for (uint32_t i = blockIdx.x * NTHR + threadIdx.x; i < G; i += stride) {
        uint2 pr = pairs[i];
        uint32_t u = pr.x & MASK31;
        bool keep = (u > t) || (u == t && j > 0 && pr.y <= tieMax);
        if (keep) out[pr.y] = pr.x;
    }
}

extern "C" void kernel_launch(void* const* d_in, const int* in_sizes, int n_in,
                              void* d_out, int out_size, void* d_ws, size_t ws_size,
                              hipStream_t stream) {
    const uint32_t* x = (const uint32_t*)d_in[0];
    uint32_t* out = (uint32_t*)d_out;
    uint32_t* ws = (uint32_t*)d_ws;
    long long n = (long long)in_sizes[0];

    const double ratio = 0.5;  // SPARSE_COMPRESSION_RATIO
    long long k = (long long)((double)n * (1.0 - ratio));
    if (k < 1) k = 1;
    if (k > n) k = n;

    long long n4 = n >> 2;
    long long S = (n4 >> 5) << 2;           // 4 samples per 32 uint4s
    long long ks = (long long)((double)k * ((double)S / (double)n));
    const long long M = 4500;               // ~8.8 sigma at S=1,048,576
    uint32_t ksmM = (uint32_t)((ks - M) < 1 ? 1 : (ks - M));
    uint32_t kspM = (uint32_t)((ks + M) > S ? S : (ks + M));

    zero_ws_kernel<<<(ZERO_WORDS + NTHR - 1) / NTHR, NTHR, 0, stream>>>(ws);
    sample_hist_kernel<<<512, NTHR, 0, stream>>>((const uint4*)x, n4, ws);
    sel_bracket_kernel<<<1, NTHR, 0, stream>>>(ws, ksmM, kspM);
    fused_main_kernel<<<2048, NTHR, 0, stream>>>(x, out, n, ws);
    cand_hist_kernel<<<256, NTHR, 0, stream>>>(ws);
    sel_gather_kernel<<<256, NTHR, 0, stream>>>(ws, (uint32_t)k);
    final_fixup_kernel<<<256, NTHR, 0, stream>>>(ws, out);
}